// Round 6
// baseline (948.592 us; speedup 1.0000x reference)
//
#include <hip/hip_runtime.h>
#include <cstdint>

#define TOKENS 8192
#define H_DIM  1024
#define F_DIM  4096
#define E_NUM  8
#define ASSIGN (TOKENS * 2)   // top_k = 2
#define MAXSEG 144            // sum ceil(Ne/128) <= 16384/128 + 8 = 136
#define GEMM2_W 1024          // persistent workers for phase 2 (4 blocks/CU)

using short8 = __attribute__((ext_vector_type(8))) short;
using f32x4  = __attribute__((ext_vector_type(4))) float;

__device__ __forceinline__ unsigned short f32_to_bf16(float f) {
  unsigned int u = __float_as_uint(f);
  u += 0x7FFFu + ((u >> 16) & 1u);   // round-to-nearest-even
  return (unsigned short)(u >> 16);
}

// 16B direct global->LDS (DMA). Dest = wave-uniform base + lane*16.
__device__ __forceinline__ void direct_load16(const void* g, void* l) {
  __builtin_amdgcn_global_load_lds(
      (const __attribute__((address_space(1))) unsigned int*)(uintptr_t)g,
      (__attribute__((address_space(3))) unsigned int*)(uintptr_t)l,
      16, 0, 0);
}

// ---------------- fused prep: convert x + router, transpose w1/w2 ----------
// blocks [0,8192): convert x -> bf16 AND route its token (row is in regs)
// blocks [8192,16384): transpose w1 [8][1024][4096] -> w1t [8][4096][1024]
// blocks [16384,24576): transpose w2 [8][4096][1024] -> w2t [8][1024][4096]
__device__ __forceinline__ void transpose_tile(
    const float* __restrict__ src, unsigned short* __restrict__ dst,
    int R, int C, int e, int bx, int by, int tid) {
  __shared__ unsigned short t[64][68];   // t[c][r]
  size_t base = (size_t)e * R * C;
  int c0 = bx * 64, r0 = by * 64;
  int rl = tid >> 4, c4 = (tid & 15) * 4;
#pragma unroll
  for (int i = 0; i < 4; ++i) {
    int r = rl + 16 * i;
    float4 v = *(const float4*)(src + base + (size_t)(r0 + r) * C + c0 + c4);
    t[c4 + 0][r] = f32_to_bf16(v.x);
    t[c4 + 1][r] = f32_to_bf16(v.y);
    t[c4 + 2][r] = f32_to_bf16(v.z);
    t[c4 + 3][r] = f32_to_bf16(v.w);
  }
  __syncthreads();
  int cc = tid >> 3, rr = (tid & 7) * 8;
#pragma unroll
  for (int i = 0; i < 2; ++i) {
    int c = cc + 32 * i;
#pragma unroll
    for (int j = 0; j < 2; ++j) {
      ushort4 v = *(const ushort4*)&t[c][rr + 4 * j];
      *(ushort4*)(dst + base + (size_t)(c0 + c) * R + r0 + rr + 4 * j) = v;
    }
  }
}

__global__ __launch_bounds__(256) void prep_kernel(
    const float* __restrict__ x, const float* __restrict__ w1, const float* __restrict__ w2,
    const float* __restrict__ rw, const float* __restrict__ rb,
    unsigned short* __restrict__ xb, unsigned short* __restrict__ w1t,
    unsigned short* __restrict__ w2t,
    int2* __restrict__ tok_e, float2* __restrict__ tok_w) {
  __shared__ float rsum[4][8];
  int id = blockIdx.x, tid = threadIdx.x;
  if (id < 8192) {
    // block id == token id; thread tid holds x[id][tid*4 .. tid*4+3]
    float4 v = ((const float4*)x)[id * 256 + tid];
    ushort4 o;
    o.x = f32_to_bf16(v.x); o.y = f32_to_bf16(v.y);
    o.z = f32_to_bf16(v.z); o.w = f32_to_bf16(v.w);
    ((ushort4*)xb)[id * 256 + tid] = o;
    // fused router: partials for 4 h-positions (rw rows tid*4.. are 128 B contig)
    float p[8];
#pragma unroll
    for (int e = 0; e < 8; ++e) p[e] = 0.f;
    const float4* w4 = (const float4*)(rw + (size_t)tid * 32);
    float xv;
#pragma unroll
    for (int j = 0; j < 4; ++j) {
      xv = (j == 0) ? v.x : (j == 1) ? v.y : (j == 2) ? v.z : v.w;
      float4 wa = w4[j * 2], wb = w4[j * 2 + 1];
      p[0] += xv * wa.x; p[1] += xv * wa.y; p[2] += xv * wa.z; p[3] += xv * wa.w;
      p[4] += xv * wb.x; p[5] += xv * wb.y; p[6] += xv * wb.z; p[7] += xv * wb.w;
    }
#pragma unroll
    for (int e = 0; e < 8; ++e)
      for (int off = 32; off > 0; off >>= 1) p[e] += __shfl_xor(p[e], off, 64);
    int wv = tid >> 6, lane = tid & 63;
    if (lane == 0) {
#pragma unroll
      for (int e = 0; e < 8; ++e) rsum[wv][e] = p[e];
    }
    __syncthreads();
    if (tid == 0) {
      float a[8];
#pragma unroll
      for (int e = 0; e < 8; ++e)
        a[e] = rsum[0][e] + rsum[1][e] + rsum[2][e] + rsum[3][e] + rb[e];
      int e0 = 0; float l0 = a[0];
#pragma unroll
      for (int e = 1; e < 8; ++e) if (a[e] > l0) { l0 = a[e]; e0 = e; }
      int e1 = -1; float l1 = -3.4e38f;
#pragma unroll
      for (int e = 0; e < 8; ++e) if (e != e0 && a[e] > l1) { l1 = a[e]; e1 = e; }
      float w0 = 1.f / (1.f + expf(l1 - l0));
      tok_e[id] = make_int2(e0, e1);
      tok_w[id] = make_float2(w0, 1.f - w0);
    }
  } else if (id < 16384) {
    int lo = id - 8192;
    transpose_tile(w1, w1t, H_DIM, F_DIM, lo >> 10, (lo & 1023) & 63, (lo & 1023) >> 6, tid);
  } else {
    int lo = id - 16384;
    transpose_tile(w2, w2t, F_DIM, H_DIM, lo >> 10, (lo & 1023) & 15, (lo & 1023) >> 4, tid);
  }
}

// ctrl int layout (1024 ints):
// [0..7]   counts          [8..16]  offsets (prefix, [16]=16384)
// [25]     nseg            [32..32+MAXSEG)   seg_e
// [256..256+MAXSEG) seg_row0
// [512..768) hist[32][8]   [768..1024) pbase[32][8]
__global__ __launch_bounds__(256) void hist_kernel(
    const int2* __restrict__ tok_e, int* __restrict__ ctrl) {
  __shared__ int lc[8];
  int tid = threadIdx.x;
  if (tid < 8) lc[tid] = 0;
  __syncthreads();
  int2 e = tok_e[blockIdx.x * 256 + tid];
  atomicAdd(&lc[e.x], 1);
  atomicAdd(&lc[e.y], 1);
  __syncthreads();
  if (tid < 8) ctrl[512 + blockIdx.x * 8 + tid] = lc[tid];
}

__global__ void plan_kernel(int* __restrict__ ctrl) {
  int lane = threadIdx.x;
  // per-expert total + per-block exclusive prefix (within expert)
  if (lane < 8) {
    int run = 0;
    for (int b = 0; b < 32; ++b) {
      ctrl[768 + b * 8 + lane] = run;
      run += ctrl[512 + b * 8 + lane];
    }
    ctrl[lane] = run;
  }
  __syncthreads();
  if (lane == 0) {
    int run = 0, ns = 0;
    ctrl[8] = 0;
    for (int e = 0; e < 8; ++e) {
      int cnt = ctrl[e];
      run += cnt;
      ctrl[9 + e] = run;
      for (int r0 = 0; r0 < cnt; r0 += 128) { ctrl[32 + ns] = e; ctrl[256 + ns] = r0; ++ns; }
    }
    ctrl[25] = ns;
  }
  __syncthreads();
  if (lane < 8) {
    int off = ctrl[8 + lane];
    for (int b = 0; b < 32; ++b) ctrl[768 + b * 8 + lane] += off;
  }
}

__global__ __launch_bounds__(256) void place_kernel(
    const int2* __restrict__ tok_e, const float2* __restrict__ tok_w,
    const int* __restrict__ ctrl, int* __restrict__ atok, float* __restrict__ aw) {
  __shared__ int lc[8];
  int tid = threadIdx.x;
  if (tid < 8) lc[tid] = 0;
  __syncthreads();
  int t = blockIdx.x * 256 + tid;
  int2 e = tok_e[t];
  float2 wv = tok_w[t];
  int l0 = atomicAdd(&lc[e.x], 1);
  int l1 = atomicAdd(&lc[e.y], 1);
  int p0 = ctrl[768 + blockIdx.x * 8 + e.x] + l0;
  int p1 = ctrl[768 + blockIdx.x * 8 + e.y] + l1;
  atok[p0] = t; aw[p0] = wv.x;
  atok[p1] = t; aw[p1] = wv.y;
}

// ---------------- grouped GEMM: 128x128 tile, BK=64, 4 waves ----------------
// C[m][n] = sum_k A[m][k] * BT[n][k].  Wave grid 2x2 (64x64 per wave),
// 16x16x32 MFMA, 4x4 acc/wave.  LDS single-buffered: A 16KB + B 16KB.
// Row = 64 ushorts = 128 B = 8 chunks of 16 B; chunk q stored at slot q^(row&7)
// -> ds_read_b128 fragment reads are 2-way (free), staging is DMA.
// 124 regs unified + 32 KB LDS -> 4 blocks/CU -> 1024 slots.

// phase 1 (gelu -> hbuf, non-splittable output): grid-scheduled as before.
template <int K, int NTOT>
__global__ __launch_bounds__(256, 4) void moe_gemm1_kernel(
    const unsigned short* __restrict__ Abase,
    const unsigned short* __restrict__ Bbase,   // [E][NTOT][K] bf16
    const float* __restrict__ bias,             // [E][NTOT]
    const int* __restrict__ ctrl,
    const int* __restrict__ atok,
    unsigned short* __restrict__ Hout) {        // h [ASSIGN][NTOT]
  const int seg = blockIdx.y;
  if (seg >= ctrl[25]) return;
  const int e = ctrl[32 + seg];
  const int row0 = ctrl[256 + seg];
  const int off_e = ctrl[8 + e];
  const int Ne = ctrl[9 + e] - off_e;
  const int n0 = blockIdx.x * 128;

  __shared__ __align__(16) unsigned short As[128 * 64];   // 16 KB
  __shared__ __align__(16) unsigned short Bs[128 * 64];   // 16 KB

  const int tid = threadIdx.x;
  const int lane = tid & 63;
  const int w = tid >> 6;          // 0..3
  const int wm = w >> 1, wn = w & 1;
  const int lrow = lane >> 3;      // 0..7
  const int q = (lane & 7) ^ lrow; // data chunk fetched by this lane

  unsigned int goff[8];            // element offset from Abase/Bbase (32-bit)
#pragma unroll
  for (int j = 0; j < 8; ++j) {
    int t = w * 8 + j;             // 0..31
    if (t < 16) {                  // A rows 0..127
      int r = row0 + t * 8 + lrow;
      if (r > Ne - 1) r = Ne - 1;
      goff[j] = (unsigned int)atok[off_e + r] * (unsigned int)K + q * 8;
    } else {                       // B rows 0..127
      int brow = (t - 16) * 8 + lrow;
      goff[j] = (unsigned int)((size_t)e * NTOT * K + (size_t)(n0 + brow) * K) + q * 8;
    }
  }

  const int quad = lane >> 4, l15 = lane & 15, l7 = lane & 7;

  f32x4 acc[4][4];
#pragma unroll
  for (int i = 0; i < 4; ++i)
#pragma unroll
    for (int j = 0; j < 4; ++j) acc[i][j] = f32x4{0.f, 0.f, 0.f, 0.f};

  for (int k0 = 0; k0 < K; k0 += 64) {
    __syncthreads();   // previous compute done before LDS overwrite
#pragma unroll
    for (int j = 0; j < 8; ++j) {
      int t = w * 8 + j;
      unsigned short* dst = (t < 16) ? &As[t * 512] : &Bs[(t - 16) * 512];
      const unsigned short* src = (t < 16) ? Abase : Bbase;
      direct_load16(src + goff[j] + k0, dst);
    }
    __syncthreads();   // staged data visible
#pragma unroll
    for (int ks = 0; ks < 2; ++ks) {
      short8 af[4], bfr[4];
      const int c = ((ks * 4 + quad) ^ l7) * 8;
#pragma unroll
      for (int i = 0; i < 4; ++i)
        af[i] = *(const short8*)&As[(wm * 64 + i * 16 + l15) * 64 + c];
#pragma unroll
      for (int j = 0; j < 4; ++j)
        bfr[j] = *(const short8*)&Bs[(wn * 64 + j * 16 + l15) * 64 + c];
#pragma unroll
      for (int i = 0; i < 4; ++i)
#pragma unroll
        for (int j = 0; j < 4; ++j)
          acc[i][j] = __builtin_amdgcn_mfma_f32_16x16x32_bf16(af[i], bfr[j], acc[i][j], 0, 0, 0);
    }
  }

  // epilogue: C row = quad*4+reg, col = lane&15
#pragma unroll
  for (int j = 0; j < 4; ++j) {
    int gn = n0 + wn * 64 + j * 16 + l15;
    float bv = bias[(size_t)e * NTOT + gn];
#pragma unroll
    for (int i = 0; i < 4; ++i) {
      int gmb = row0 + wm * 64 + i * 16 + quad * 4;
#pragma unroll
      for (int r = 0; r < 4; ++r) {
        int gm = gmb + r;
        if (gm < Ne) {
          float v = acc[i][j][r] + bv;
          // gelu(tanh approx) == v * sigmoid(2u), u = 0.7978845608(v + 0.044715 v^3)
          float ex = __expf(-1.5957691216057308f * (v + 0.044715f * v * v * v));
          float g = v * __builtin_amdgcn_rcpf(1.f + ex);
          Hout[(size_t)(off_e + gm) * NTOT + gn] = f32_to_bf16(g);
        }
      }
    }
  }
}

// phase 2 (atomic output -> K-divisible): PERSISTENT balanced-span schedule.
// Total work in BK=64 grains G = nseg*(NTOT/128)*(K/64); W=1024 resident
// workers each take a contiguous grain span of q or q+1 grains -> every
// worker finishes within one grain of the bulk time.  Round-2/5 counters:
// the old grid schedule paid a ~110us tail where 64 spill items ran at
// ~6% occupancy (time-avg 32%, MfmaUtil 22).  A span crosses <=2 item
// boundaries (<=3 pieces); each piece atomically accumulates its partial
// K-sum (bias added only by the ko==0 piece, same algebra as verified
// round-1 split-K).
template <int K, int NTOT>
__global__ __launch_bounds__(256, 4) void moe_gemm2_kernel(
    const unsigned short* __restrict__ Abase,
    const unsigned short* __restrict__ Bbase,   // [E][NTOT][K] bf16
    const float* __restrict__ bias,             // [E][NTOT]
    const int* __restrict__ ctrl,
    const int* __restrict__ atok,
    const float* __restrict__ aw,
    float* __restrict__ Out) {                  // out [TOKENS][NTOT]
  constexpr int NX  = NTOT / 128;   // 8
  constexpr int GPI = K / 64;       // 64 grains per item
  const int nseg = ctrl[25];
  const int G = nseg * NX * GPI;
  const int W = (int)gridDim.x;
  const int qg = G / W, rg = G % W;
  const int b = (int)blockIdx.x;
  int g0   = b * qg + (b < rg ? b : rg);
  int gend = g0 + qg + (b < rg ? 1 : 0);

  __shared__ __align__(16) unsigned short As[128 * 64];   // 16 KB
  __shared__ __align__(16) unsigned short Bs[128 * 64];   // 16 KB

  const int tid = threadIdx.x;
  const int lane = tid & 63;
  const int w = tid >> 6;          // 0..3
  const int wm = w >> 1, wn = w & 1;
  const int lrow = lane >> 3;      // 0..7
  const int qc = (lane & 7) ^ lrow;
  const int quad = lane >> 4, l15 = lane & 15, l7 = lane & 7;

  while (g0 < gend) {
    const int item = g0 / GPI;
    const int ko   = g0 - item * GPI;       // starting grain within item
    int glen = gend - g0;
    if (glen > GPI - ko) glen = GPI - ko;

    const int seg = item / NX;
    const int x   = item - seg * NX;
    const int e = ctrl[32 + seg];
    const int row0 = ctrl[256 + seg];
    const int off_e = ctrl[8 + e];
    const int Ne = ctrl[9 + e] - off_e;
    const int n0 = x * 128;

    unsigned int goff[8];
#pragma unroll
    for (int j = 0; j < 8; ++j) {
      int t = w * 8 + j;
      if (t < 16) {                  // A rows (phase2: contiguous hbuf rows)
        int r = row0 + t * 8 + lrow;
        if (r > Ne - 1) r = Ne - 1;
        goff[j] = (unsigned int)(off_e + r) * (unsigned int)K + qc * 8;
      } else {                       // B rows
        int brow = (t - 16) * 8 + lrow;
        goff[j] = (unsigned int)((size_t)e * NTOT * K + (size_t)(n0 + brow) * K) + qc * 8;
      }
    }

    f32x4 acc[4][4];
#pragma unroll
    for (int i = 0; i < 4; ++i)
#pragma unroll
      for (int j = 0; j < 4; ++j) acc[i][j] = f32x4{0.f, 0.f, 0.f, 0.f};

    for (int kk = 0; kk < glen; ++kk) {
      const int k0 = (ko + kk) * 64;
      __syncthreads();   // previous compute done before LDS overwrite
#pragma unroll
      for (int j = 0; j < 8; ++j) {
        int t = w * 8 + j;
        unsigned short* dst = (t < 16) ? &As[t * 512] : &Bs[(t - 16) * 512];
        const unsigned short* src = (t < 16) ? Abase : Bbase;
        direct_load16(src + goff[j] + k0, dst);
      }
      __syncthreads();   // staged data visible
#pragma unroll
      for (int ks = 0; ks < 2; ++ks) {
        short8 af[4], bfr[4];
        const int c = ((ks * 4 + quad) ^ l7) * 8;
#pragma unroll
        for (int i = 0; i < 4; ++i)
          af[i] = *(const short8*)&As[(wm * 64 + i * 16 + l15) * 64 + c];
#pragma unroll
        for (int j = 0; j < 4; ++j)
          bfr[j] = *(const short8*)&Bs[(wn * 64 + j * 16 + l15) * 64 + c];
#pragma unroll
        for (int i = 0; i < 4; ++i)
#pragma unroll
          for (int j = 0; j < 4; ++j)
            acc[i][j] = __builtin_amdgcn_mfma_f32_16x16x32_bf16(af[i], bfr[j], acc[i][j], 0, 0, 0);
      }
    }

    // epilogue: partial K-sum atomically accumulated; bias once (ko==0 piece)
#pragma unroll
    for (int j = 0; j < 4; ++j) {
      int gn = n0 + wn * 64 + j * 16 + l15;
      float bv = (ko == 0) ? bias[(size_t)e * NTOT + gn] : 0.f;
#pragma unroll
      for (int i = 0; i < 4; ++i) {
        int gmb = row0 + wm * 64 + i * 16 + quad * 4;
#pragma unroll
        for (int r = 0; r < 4; ++r) {
          int gm = gmb + r;
          if (gm < Ne) {
            float v = acc[i][j][r] + bv;
            int tok = atok[off_e + gm];
            float wt = aw[off_e + gm];
            atomicAdd(Out + (size_t)tok * NTOT + gn, v * wt);
          }
        }
      }
    }

    g0 += glen;
  }
}

extern "C" void kernel_launch(void* const* d_in, const int* in_sizes, int n_in,
                              void* d_out, int out_size, void* d_ws, size_t ws_size,
                              hipStream_t stream) {
  const float* x  = (const float*)d_in[0];
  const float* rw = (const float*)d_in[1];
  const float* rb = (const float*)d_in[2];
  const float* w1 = (const float*)d_in[3];
  const float* b1 = (const float*)d_in[4];
  const float* w2 = (const float*)d_in[5];
  const float* b2 = (const float*)d_in[6];
  float* out = (float*)d_out;

  char* ws = (char*)d_ws;
  size_t off = 0;
  auto take = [&](size_t b) { char* p = ws + off; off = (off + b + 255) & ~(size_t)255; return p; };
  unsigned short* xb   = (unsigned short*)take((size_t)TOKENS * H_DIM * 2);
  unsigned short* w1t  = (unsigned short*)take((size_t)E_NUM * F_DIM * H_DIM * 2);
  unsigned short* w2t  = (unsigned short*)take((size_t)E_NUM * H_DIM * F_DIM * 2);
  unsigned short* hbuf = (unsigned short*)take((size_t)ASSIGN * F_DIM * 2);
  int2*   tok_e = (int2*)take(TOKENS * sizeof(int2));
  float2* tok_w = (float2*)take(TOKENS * sizeof(float2));
  int*    atok  = (int*)take(ASSIGN * 4);
  float*  aw    = (float*)take(ASSIGN * 4);
  int*    ctrl  = (int*)take(4096);

  hipMemsetAsync(out, 0, (size_t)out_size * 4, stream);

  prep_kernel<<<24576, 256, 0, stream>>>(x, w1, w2, rw, rb, xb, w1t, w2t, tok_e, tok_w);
  hist_kernel<<<TOKENS / 256, 256, 0, stream>>>(tok_e, ctrl);
  plan_kernel<<<1, 64, 0, stream>>>(ctrl);
  place_kernel<<<TOKENS / 256, 256, 0, stream>>>(tok_e, tok_w, ctrl, atok, aw);
  moe_gemm1_kernel<H_DIM, F_DIM><<<dim3(F_DIM / 128, MAXSEG), 256, 0, stream>>>(
      xb, w1t, b1, ctrl, atok, hbuf);
  moe_gemm2_kernel<F_DIM, H_DIM><<<GEMM2_W, 256, 0, stream>>>(
      hbuf, w2t, b2, ctrl, atok, aw, out);
}

// Round 8
// 810.983 us; speedup vs baseline: 1.1697x; 1.1697x over previous
//
#include <hip/hip_runtime.h>
#include <cstdint>

#define TOKENS 8192
#define H_DIM  1024
#define F_DIM  4096
#define E_NUM  8
#define ASSIGN (TOKENS * 2)   // top_k = 2
#define MAXSEG 144            // sum ceil(Ne/128) <= 16384/128 + 8 = 136

using short8 = __attribute__((ext_vector_type(8))) short;
using f32x4  = __attribute__((ext_vector_type(4))) float;

__device__ __forceinline__ unsigned short f32_to_bf16(float f) {
  unsigned int u = __float_as_uint(f);
  u += 0x7FFFu + ((u >> 16) & 1u);   // round-to-nearest-even
  return (unsigned short)(u >> 16);
}

// 16B direct global->LDS (DMA). Dest = wave-uniform base + lane*16.
__device__ __forceinline__ void direct_load16(const void* g, void* l) {
  __builtin_amdgcn_global_load_lds(
      (const __attribute__((address_space(1))) unsigned int*)(uintptr_t)g,
      (__attribute__((address_space(3))) unsigned int*)(uintptr_t)l,
      16, 0, 0);
}

// ---------------- fused prep: convert x, transpose w1/w2, router ----------
// blocks [0,8192): convert x -> bf16
// blocks [8192,16384): transpose w1 [8][1024][4096] -> w1t [8][4096][1024]
// blocks [16384,24576): transpose w2 [8][4096][1024] -> w2t [8][1024][4096]
// blocks [24576,26624): router (4 tokens / block) — writes tok_e/tok_w only
__device__ __forceinline__ void transpose_tile(
    const float* __restrict__ src, unsigned short* __restrict__ dst,
    int R, int C, int e, int bx, int by, int tid) {
  __shared__ unsigned short t[64][68];   // t[c][r]
  size_t base = (size_t)e * R * C;
  int c0 = bx * 64, r0 = by * 64;
  int rl = tid >> 4, c4 = (tid & 15) * 4;
#pragma unroll
  for (int i = 0; i < 4; ++i) {
    int r = rl + 16 * i;
    float4 v = *(const float4*)(src + base + (size_t)(r0 + r) * C + c0 + c4);
    t[c4 + 0][r] = f32_to_bf16(v.x);
    t[c4 + 1][r] = f32_to_bf16(v.y);
    t[c4 + 2][r] = f32_to_bf16(v.z);
    t[c4 + 3][r] = f32_to_bf16(v.w);
  }
  __syncthreads();
  int cc = tid >> 3, rr = (tid & 7) * 8;
#pragma unroll
  for (int i = 0; i < 2; ++i) {
    int c = cc + 32 * i;
#pragma unroll
    for (int j = 0; j < 2; ++j) {
      ushort4 v = *(const ushort4*)&t[c][rr + 4 * j];
      *(ushort4*)(dst + base + (size_t)(c0 + c) * R + r0 + rr + 4 * j) = v;
    }
  }
}

__global__ __launch_bounds__(256) void prep_kernel(
    const float* __restrict__ x, const float* __restrict__ w1, const float* __restrict__ w2,
    const float* __restrict__ rw, const float* __restrict__ rb,
    unsigned short* __restrict__ xb, unsigned short* __restrict__ w1t,
    unsigned short* __restrict__ w2t,
    int2* __restrict__ tok_e, float2* __restrict__ tok_w) {
  int id = blockIdx.x, tid = threadIdx.x;
  if (id < 8192) {
    int i = id * 256 + tid;
    float4 v = ((const float4*)x)[i];
    ushort4 o;
    o.x = f32_to_bf16(v.x); o.y = f32_to_bf16(v.y);
    o.z = f32_to_bf16(v.z); o.w = f32_to_bf16(v.w);
    ((ushort4*)xb)[i] = o;
  } else if (id < 16384) {
    int lo = id - 8192;
    transpose_tile(w1, w1t, H_DIM, F_DIM, lo >> 10, (lo & 1023) & 63, (lo & 1023) >> 6, tid);
  } else if (id < 24576) {
    int lo = id - 16384;
    transpose_tile(w2, w2t, F_DIM, H_DIM, lo >> 10, (lo & 1023) & 15, (lo & 1023) >> 4, tid);
  } else {
    int t = (id - 24576) * 4 + (tid >> 6);
    int lane = tid & 63;
    float acc[8];
#pragma unroll
    for (int e = 0; e < 8; ++e) acc[e] = 0.f;
    const float* xr = x + (long)t * H_DIM;
#pragma unroll 4
    for (int j = 0; j < H_DIM / 64; ++j) {
      int hh = lane + 64 * j;
      float xv = xr[hh];
      const float4* w4 = (const float4*)(rw + (long)hh * 8);
      float4 wa = w4[0], wb = w4[1];
      acc[0] += xv * wa.x; acc[1] += xv * wa.y; acc[2] += xv * wa.z; acc[3] += xv * wa.w;
      acc[4] += xv * wb.x; acc[5] += xv * wb.y; acc[6] += xv * wb.z; acc[7] += xv * wb.w;
    }
#pragma unroll
    for (int e = 0; e < 8; ++e) {
      float v = acc[e];
      for (int off = 32; off > 0; off >>= 1) v += __shfl_xor(v, off, 64);
      acc[e] = v + rb[e];
    }
    if (lane == 0) {
      int e0 = 0; float l0 = acc[0];
#pragma unroll
      for (int e = 1; e < 8; ++e) if (acc[e] > l0) { l0 = acc[e]; e0 = e; }
      int e1 = -1; float l1 = -3.4e38f;
#pragma unroll
      for (int e = 0; e < 8; ++e) if (e != e0 && acc[e] > l1) { l1 = acc[e]; e1 = e; }
      float w0 = 1.f / (1.f + expf(l1 - l0));
      tok_e[t] = make_int2(e0, e1);
      tok_w[t] = make_float2(w0, 1.f - w0);
    }
  }
}

// ctrl int layout (1024 ints):
// [0..7]   counts          [8..16]  offsets (prefix, [16]=16384)
// [25]     nseg            [32..32+MAXSEG)   seg_e
// [256..256+MAXSEG) seg_row0
// [512..768) hist[32][8]   [768..1024) pbase[32][8]
__global__ __launch_bounds__(256) void hist_kernel(
    const int2* __restrict__ tok_e, int* __restrict__ ctrl) {
  __shared__ int lc[8];
  int tid = threadIdx.x;
  if (tid < 8) lc[tid] = 0;
  __syncthreads();
  int2 e = tok_e[blockIdx.x * 256 + tid];
  atomicAdd(&lc[e.x], 1);
  atomicAdd(&lc[e.y], 1);
  __syncthreads();
  if (tid < 8) ctrl[512 + blockIdx.x * 8 + tid] = lc[tid];
}

__global__ void plan_kernel(int* __restrict__ ctrl) {
  int lane = threadIdx.x;
  // per-expert total + per-block exclusive prefix (within expert)
  if (lane < 8) {
    int run = 0;
    for (int b = 0; b < 32; ++b) {
      ctrl[768 + b * 8 + lane] = run;
      run += ctrl[512 + b * 8 + lane];
    }
    ctrl[lane] = run;
  }
  __syncthreads();
  if (lane == 0) {
    int run = 0, ns = 0;
    ctrl[8] = 0;
    for (int e = 0; e < 8; ++e) {
      int cnt = ctrl[e];
      run += cnt;
      ctrl[9 + e] = run;
      for (int r0 = 0; r0 < cnt; r0 += 128) { ctrl[32 + ns] = e; ctrl[256 + ns] = r0; ++ns; }
    }
    ctrl[25] = ns;
  }
  __syncthreads();
  if (lane < 8) {
    int off = ctrl[8 + lane];
    for (int b = 0; b < 32; ++b) ctrl[768 + b * 8 + lane] += off;
  }
}

__global__ __launch_bounds__(256) void place_kernel(
    const int2* __restrict__ tok_e, const float2* __restrict__ tok_w,
    const int* __restrict__ ctrl, int* __restrict__ atok, float* __restrict__ aw) {
  __shared__ int lc[8];
  int tid = threadIdx.x;
  if (tid < 8) lc[tid] = 0;
  __syncthreads();
  int t = blockIdx.x * 256 + tid;
  int2 e = tok_e[t];
  float2 wv = tok_w[t];
  int l0 = atomicAdd(&lc[e.x], 1);
  int l1 = atomicAdd(&lc[e.y], 1);
  int p0 = ctrl[768 + blockIdx.x * 8 + e.x] + l0;
  int p1 = ctrl[768 + blockIdx.x * 8 + e.y] + l1;
  atok[p0] = t; aw[p0] = wv.x;
  atok[p1] = t; aw[p1] = wv.y;
}

// ---------------- grouped GEMM: 128x128 tile, BK=64, 4 waves ----------------
// C[m][n] = sum_k A[m][k] * BT[n][k].  Wave grid 2x2 (64x64 per wave),
// 16x16x32 MFMA, 4x4 acc/wave.  LDS single-buffered: A 16KB + B 16KB.
// Row = 64 ushorts = 128 B = 8 chunks of 16 B; chunk q stored at slot q^(row&7)
// -> ds_read_b128 fragment reads are 2-way (free), staging is DMA.
// 124 regs unified + 32 KB LDS -> 4 blocks/CU -> 1024 block slots.
//
// PHASE2 SPLIT TAIL (the one change vs the verified 843us kernel): segs
// 0..127 (= exactly 1024 items = one full co-resident round, lockstep k,
// preserving A-seg L2 sharing) are full-K, dispatched first.  Overflow
// segs 128..135 (the former ~110us straggler round at ~6% occupancy) are
// K-split 4-ways into <=256 quarter-items dispatched LAST so they
// backfill round 1's drain.  Atomic f32 output makes K-splitting exact
// (round-1-verified algebra); bias only on the k_begin==0 piece.
template <int K, int NTOT, bool PHASE2>
__global__ __launch_bounds__(256, 4) void moe_gemm_kernel(
    const unsigned short* __restrict__ Abase,
    const unsigned short* __restrict__ Bbase,   // [E][NTOT][K] bf16
    const float* __restrict__ bias,             // [E][NTOT]
    const int* __restrict__ ctrl,
    const int* __restrict__ atok,
    const float* __restrict__ aw,
    unsigned short* __restrict__ Hout,          // phase1: h [ASSIGN][NTOT]
    float* __restrict__ Out) {                  // phase2: out [TOKENS][NTOT]
  int seg, k_begin, k_len;
  if (!PHASE2) {
    seg = blockIdx.y; k_begin = 0; k_len = K;
  } else {
    const int y = blockIdx.y;
    if (y < 128) { seg = y; k_begin = 0; k_len = K; }
    else {
      const int idx = y - 128;                  // 0..31
      seg = 128 + (idx & 7);
      k_begin = (idx >> 3) * (K / 4);
      k_len = K / 4;
    }
  }
  if (seg >= ctrl[25]) return;
  const int e = ctrl[32 + seg];
  const int row0 = ctrl[256 + seg];
  const int off_e = ctrl[8 + e];
  const int Ne = ctrl[9 + e] - off_e;
  const int n0 = blockIdx.x * 128;

  __shared__ __align__(16) unsigned short As[128 * 64];   // 16 KB
  __shared__ __align__(16) unsigned short Bs[128 * 64];   // 16 KB

  const int tid = threadIdx.x;
  const int lane = tid & 63;
  const int w = tid >> 6;          // 0..3
  const int wm = w >> 1, wn = w & 1;

  // staging: issue t = w*8+j covers 8 consecutive LDS rows; lane -> (lrow, slot)
  const int lrow = lane >> 3;      // 0..7
  const int q = (lane & 7) ^ lrow; // data chunk fetched by this lane

  unsigned int goff[8];            // element offset from Abase/Bbase (32-bit)
#pragma unroll
  for (int j = 0; j < 8; ++j) {
    int t = w * 8 + j;             // 0..31
    if (t < 16) {                  // A rows 0..127
      int r = row0 + t * 8 + lrow;
      if (r > Ne - 1) r = Ne - 1;
      unsigned int srow = PHASE2 ? (unsigned int)(off_e + r) : (unsigned int)atok[off_e + r];
      goff[j] = srow * (unsigned int)K + q * 8;
    } else {                       // B rows 0..127
      int brow = (t - 16) * 8 + lrow;
      goff[j] = (unsigned int)((size_t)e * NTOT * K + (size_t)(n0 + brow) * K) + q * 8;
    }
  }

  const int quad = lane >> 4, l15 = lane & 15, l7 = lane & 7;

  f32x4 acc[4][4];
#pragma unroll
  for (int i = 0; i < 4; ++i)
#pragma unroll
    for (int j = 0; j < 4; ++j) acc[i][j] = f32x4{0.f, 0.f, 0.f, 0.f};

  for (int k0 = k_begin; k0 < k_begin + k_len; k0 += 64) {
    __syncthreads();   // previous compute done before LDS overwrite
#pragma unroll
    for (int j = 0; j < 8; ++j) {
      int t = w * 8 + j;
      unsigned short* dst = (t < 16) ? &As[t * 512] : &Bs[(t - 16) * 512];
      const unsigned short* src = (t < 16) ? Abase : Bbase;
      direct_load16(src + goff[j] + k0, dst);
    }
    __syncthreads();   // staged data visible
#pragma unroll
    for (int ks = 0; ks < 2; ++ks) {
      short8 af[4], bfr[4];
      const int c = ((ks * 4 + quad) ^ l7) * 8;
#pragma unroll
      for (int i = 0; i < 4; ++i)
        af[i] = *(const short8*)&As[(wm * 64 + i * 16 + l15) * 64 + c];
#pragma unroll
      for (int j = 0; j < 4; ++j)
        bfr[j] = *(const short8*)&Bs[(wn * 64 + j * 16 + l15) * 64 + c];
#pragma unroll
      for (int i = 0; i < 4; ++i)
#pragma unroll
        for (int j = 0; j < 4; ++j)
          acc[i][j] = __builtin_amdgcn_mfma_f32_16x16x32_bf16(af[i], bfr[j], acc[i][j], 0, 0, 0);
    }
  }

  // epilogue: C row = quad*4+reg, col = lane&15
#pragma unroll
  for (int j = 0; j < 4; ++j) {
    int gn = n0 + wn * 64 + j * 16 + l15;
    float bv = (k_begin == 0) ? bias[(size_t)e * NTOT + gn] : 0.f;
#pragma unroll
    for (int i = 0; i < 4; ++i) {
      int gmb = row0 + wm * 64 + i * 16 + quad * 4;
#pragma unroll
      for (int r = 0; r < 4; ++r) {
        int gm = gmb + r;
        if (gm < Ne) {
          float v = acc[i][j][r] + bv;
          if (!PHASE2) {
            // gelu(tanh approx) == v * sigmoid(2u), u = 0.7978845608(v + 0.044715 v^3)
            float ex = __expf(-1.5957691216057308f * (v + 0.044715f * v * v * v));
            float g = v * __builtin_amdgcn_rcpf(1.f + ex);
            Hout[(size_t)(off_e + gm) * NTOT + gn] = f32_to_bf16(g);
          } else {
            int tok = atok[off_e + gm];
            float wt = aw[off_e + gm];
            atomicAdd(Out + (size_t)tok * NTOT + gn, v * wt);
          }
        }
      }
    }
  }
}

extern "C" void kernel_launch(void* const* d_in, const int* in_sizes, int n_in,
                              void* d_out, int out_size, void* d_ws, size_t ws_size,
                              hipStream_t stream) {
  const float* x  = (const float*)d_in[0];
  const float* rw = (const float*)d_in[1];
  const float* rb = (const float*)d_in[2];
  const float* w1 = (const float*)d_in[3];
  const float* b1 = (const float*)d_in[4];
  const float* w2 = (const float*)d_in[5];
  const float* b2 = (const float*)d_in[6];
  float* out = (float*)d_out;

  char* ws = (char*)d_ws;
  size_t off = 0;
  auto take = [&](size_t b) { char* p = ws + off; off = (off + b + 255) & ~(size_t)255; return p; };
  unsigned short* xb   = (unsigned short*)take((size_t)TOKENS * H_DIM * 2);
  unsigned short* w1t  = (unsigned short*)take((size_t)E_NUM * F_DIM * H_DIM * 2);
  unsigned short* w2t  = (unsigned short*)take((size_t)E_NUM * H_DIM * F_DIM * 2);
  unsigned short* hbuf = (unsigned short*)take((size_t)ASSIGN * F_DIM * 2);
  int2*   tok_e = (int2*)take(TOKENS * sizeof(int2));
  float2* tok_w = (float2*)take(TOKENS * sizeof(float2));
  int*    atok  = (int*)take(ASSIGN * 4);
  float*  aw    = (float*)take(ASSIGN * 4);
  int*    ctrl  = (int*)take(4096);

  hipMemsetAsync(out, 0, (size_t)out_size * 4, stream);

  prep_kernel<<<26624, 256, 0, stream>>>(x, w1, w2, rw, rb, xb, w1t, w2t, tok_e, tok_w);
  hist_kernel<<<TOKENS / 256, 256, 0, stream>>>(tok_e, ctrl);
  plan_kernel<<<1, 64, 0, stream>>>(ctrl);
  place_kernel<<<TOKENS / 256, 256, 0, stream>>>(tok_e, tok_w, ctrl, atok, aw);
  moe_gemm_kernel<H_DIM, F_DIM, false><<<dim3(F_DIM / 128, MAXSEG), 256, 0, stream>>>(
      xb, w1t, b1, ctrl, atok, aw, hbuf, nullptr);
  // y: 128 bulk segs (one exact round) + 32 rows of K-split tail quarters
  moe_gemm_kernel<F_DIM, H_DIM, true><<<dim3(H_DIM / 128, 160), 256, 0, stream>>>(
      hbuf, w2t, b2, ctrl, atok, aw, nullptr, out);
}